// Round 1
// baseline (2486.380 us; speedup 1.0000x reference)
//
#include <hip/hip_runtime.h>
#include <math.h>

#define BB  8
#define KTT 2
#define THH 12
#define NN  2048
#define DII 32
#define DHD 64
#define DEE 24
#define CC  96
#define BT  16      // BB*KTT
#define RT  64      // row tile
#define MT  64      // m tile
#define PR  68      // padded stride for p[m][r]

// ---------------- emb = LN(node_emb + time_emb) * g + b (eps 1e-12) ----------
__global__ void k_emb(const float* __restrict__ node_emb,
                      const float* __restrict__ time_emb,
                      const float* __restrict__ gA,
                      const float* __restrict__ bA,
                      float* __restrict__ emb) {
  int idx = blockIdx.x * 256 + threadIdx.x;   // bt*NN + n, exact grid
  int n  = idx & (NN - 1);
  int bt = idx >> 11;
  float v[DEE];
  float mean = 0.f;
#pragma unroll
  for (int d = 0; d < DEE; ++d) {
    v[d] = node_emb[n * DEE + d] + time_emb[bt * DEE + d];
    mean += v[d];
  }
  mean *= (1.f / DEE);
  float var = 0.f;
#pragma unroll
  for (int d = 0; d < DEE; ++d) { float u = v[d] - mean; var += u * u; }
  var *= (1.f / DEE);
  float inv = 1.f / sqrtf(var + 1e-12f);
#pragma unroll
  for (int d = 0; d < DEE; ++d)
    emb[(size_t)idx * DEE + d] = (v[d] - mean) * inv * gA[d] + bA[d];
}

// ---------------- fused graph attention: Ax = softmax(emb embT) @ xin --------
// MODE 0: xin = concat(x, state) ; MODE 1: xin = concat(x, z*state)
template <int MODE>
__global__ __launch_bounds__(256, 2) void k_flash(
    const float* __restrict__ emb, const float* __restrict__ x,
    const float* __restrict__ states, const float* __restrict__ zbuf,
    float* __restrict__ Ax) {
  __shared__ alignas(16) float s_er[DEE * RT];   // [d][r] transposed
  __shared__ alignas(16) float s_em[DEE * MT];   // [d][m] transposed
  __shared__ alignas(16) float s_xin[MT * CC];   // [m][c]
  __shared__ alignas(16) float s_p[MT * PR];     // [m][r] scores^T / probs
  __shared__ float s_mi[RT];
  __shared__ float s_li[RT];
  __shared__ float s_al[RT];

  const int t  = threadIdx.x;
  const int bt = blockIdx.y;
  const int b  = bt >> 1;
  const int tt = bt & 1;
  const int rbase = blockIdx.x * RT;
  const int rg = t >> 4, cg = t & 15;
  const int r0 = rg * 4, m0 = cg * 4, c0 = cg * 6;

  {
    const float* src = emb + ((size_t)bt * NN + rbase) * DEE;
#pragma unroll
    for (int k2 = 0; k2 < 6; ++k2) {
      int e = t + 256 * k2;
      int row = e / DEE, d = e - row * DEE;
      s_er[d * RT + row] = src[e];
    }
  }
  if (t < RT) { s_mi[t] = -1e30f; s_li[t] = 0.f; }

  float acc[4][6];
#pragma unroll
  for (int i = 0; i < 4; ++i)
#pragma unroll
    for (int j = 0; j < 6; ++j) acc[i][j] = 0.f;

  for (int mt = 0; mt < NN / MT; ++mt) {
    const int mbase = mt * MT;
    __syncthreads();   // protect previous-iter s_em/s_xin/s_p
    {
      const float* src = emb + ((size_t)bt * NN + mbase) * DEE;
#pragma unroll
      for (int k2 = 0; k2 < 6; ++k2) {
        int e = t + 256 * k2;
        int row = e / DEE, d = e - row * DEE;
        s_em[d * MT + row] = src[e];
      }
    }
#pragma unroll
    for (int k2 = 0; k2 < 24; ++k2) {
      int e = t + 256 * k2;          // 6144 = MT*CC
      int m = e / CC, c = e - m * CC;
      int gn = mbase + m;
      float v;
      if (c < DII) {
        v = x[((size_t)bt * NN + gn) * DII + c];
      } else {
        v = states[(((size_t)b * THH + (THH - KTT) + tt) * NN + gn) * DHD + (c - DII)];
        if (MODE == 1) v *= zbuf[((size_t)bt * NN + gn) * DHD + (c - DII)];
      }
      s_xin[e] = v;
    }
    __syncthreads();
    // ---- scores S[r0+i][m0+j] ----
    {
      float sc[4][4];
#pragma unroll
      for (int i = 0; i < 4; ++i)
#pragma unroll
        for (int j = 0; j < 4; ++j) sc[i][j] = 0.f;
#pragma unroll
      for (int d = 0; d < DEE; ++d) {
        const float4 e4 = *(const float4*)&s_er[d * RT + r0];
        const float4 f4 = *(const float4*)&s_em[d * MT + m0];
        const float er[4] = {e4.x, e4.y, e4.z, e4.w};
        const float em[4] = {f4.x, f4.y, f4.z, f4.w};
#pragma unroll
        for (int i = 0; i < 4; ++i)
#pragma unroll
          for (int j = 0; j < 4; ++j) sc[i][j] += er[i] * em[j];
      }
#pragma unroll
      for (int i = 0; i < 4; ++i)
#pragma unroll
        for (int j = 0; j < 4; ++j)
          s_p[(m0 + j) * PR + (r0 + i)] = sc[i][j];
    }
    __syncthreads();
    // ---- online softmax, one thread per row ----
    if (t < RT) {
      const int r = t;
      float mx = s_mi[r];
      for (int m = 0; m < MT; ++m) mx = fmaxf(mx, s_p[m * PR + r]);
      float al = __expf(s_mi[r] - mx);   // 0 on first tile
      float sum = 0.f;
      for (int m = 0; m < MT; ++m) {
        float p = __expf(s_p[m * PR + r] - mx);
        s_p[m * PR + r] = p;
        sum += p;
      }
      s_li[r] = s_li[r] * al + sum;
      s_mi[r] = mx;
      s_al[r] = al;
    }
    __syncthreads();
    // ---- rescale + accumulate P @ xin ----
    {
      float al[4];
#pragma unroll
      for (int i = 0; i < 4; ++i) al[i] = s_al[r0 + i];
#pragma unroll
      for (int i = 0; i < 4; ++i)
#pragma unroll
        for (int j = 0; j < 6; ++j) acc[i][j] *= al[i];
      for (int m = 0; m < MT; ++m) {
        const float4 p4 = *(const float4*)&s_p[m * PR + r0];
        const float pv[4] = {p4.x, p4.y, p4.z, p4.w};
        const float* xp = &s_xin[m * CC + c0];
        const float2 xa = *(const float2*)xp;
        const float2 xb = *(const float2*)(xp + 2);
        const float2 xc = *(const float2*)(xp + 4);
        const float xv[6] = {xa.x, xa.y, xb.x, xb.y, xc.x, xc.y};
#pragma unroll
        for (int i = 0; i < 4; ++i)
#pragma unroll
          for (int j = 0; j < 6; ++j) acc[i][j] += pv[i] * xv[j];
      }
    }
  }
  // ---- finalize ----
#pragma unroll
  for (int i = 0; i < 4; ++i) {
    const float invl = 1.f / s_li[r0 + i];
    float* dst = &Ax[((size_t)bt * NN + rbase + r0 + i) * CC + c0];
#pragma unroll
    for (int j = 0; j < 6; ++j) dst[j] = acc[i][j] * invl;
  }
}

// ------------- per-node weight matmul: g = xg @ (node_emb@Wp) + bias ---------
template <int MODE>
__global__ __launch_bounds__(256, 2) void k_nodemm(
    const float* __restrict__ x, const float* __restrict__ states,
    const float* __restrict__ zbuf, const float* __restrict__ Ax,
    const float* __restrict__ node_emb, const float* __restrict__ time_emb,
    const float* __restrict__ Wp, const float* __restrict__ bp,
    float* __restrict__ g) {
  __shared__ alignas(16) float s_W[192 * 64];   // [ki][o]
  __shared__ float s_xg[BT * 193];              // [bt][0..191] padded
  __shared__ float s_ne[DEE];
  __shared__ float s_te[BT * DEE];

  const int t = threadIdx.x;
  const int n = blockIdx.x;

  if (t < DEE) s_ne[t] = node_emb[n * DEE + t];
  for (int e = t; e < BT * DEE; e += 256) s_te[e] = time_emb[e];
  __syncthreads();

  float ne[DEE];
#pragma unroll
  for (int d = 0; d < DEE; ++d) ne[d] = s_ne[d];

  for (int k2 = 0; k2 < 48; ++k2) {
    int j = t + 256 * k2;
    float a = 0.f;
#pragma unroll
    for (int d = 0; d < DEE; ++d) a += ne[d] * Wp[(size_t)d * 12288 + j];
    s_W[j] = a;
  }

  for (int e = t; e < BT * 192; e += 256) {
    int btv = e / 192, c = e - btv * 192;
    float v;
    if (c < DII) {
      v = x[((size_t)btv * NN + n) * DII + c];
    } else if (c < CC) {
      v = states[(((size_t)(btv >> 1) * THH + (THH - KTT) + (btv & 1)) * NN + n) * DHD + (c - DII)];
      if (MODE == 1) v *= zbuf[((size_t)btv * NN + n) * DHD + (c - DII)];
    } else {
      v = Ax[((size_t)btv * NN + n) * CC + (c - CC)];
    }
    s_xg[btv * 193 + c] = v;
  }
  __syncthreads();

  const int btv = t >> 4;          // 16 bt rows
  const int o0  = (t & 15) * 4;    // 64 outputs in 4-wide chunks
  float y[4];
#pragma unroll
  for (int q = 0; q < 4; ++q) y[q] = 0.f;
#pragma unroll
  for (int d = 0; d < DEE; ++d) {
    float te = s_te[btv * DEE + d];
#pragma unroll
    for (int q = 0; q < 4; ++q) y[q] += te * bp[d * DHD + o0 + q];
  }
  const float* xr = &s_xg[btv * 193];
  for (int i = 0; i < 192; ++i) {
    float xv = xr[i];
    const float4 w = *(const float4*)&s_W[i * 64 + o0];
    y[0] += xv * w.x; y[1] += xv * w.y; y[2] += xv * w.z; y[3] += xv * w.w;
  }
  float* dst = &g[((size_t)btv * NN + n) * DHD + o0];
#pragma unroll
  for (int q = 0; q < 4; ++q) dst[q] = y[q];
}

// --------------------- LN + tiny MHA + activation / gate ---------------------
__device__ __forceinline__ float wsum64(float v) {
#pragma unroll
  for (int off = 32; off > 0; off >>= 1) v += __shfl_xor(v, off, 64);
  return v;
}
__device__ __forceinline__ float hsum16(float v) {
  v += __shfl_xor(v, 8, 64);
  v += __shfl_xor(v, 4, 64);
  v += __shfl_xor(v, 2, 64);
  v += __shfl_xor(v, 1, 64);
  return v;
}

// MODE 0: dst = sigmoid(g + mha)  ; MODE 1: dst = r*state + (1-r)*tanh(g + mha)
template <int MODE>
__global__ void k_attn(const float* __restrict__ g,
                       const float* __restrict__ states,
                       const float* __restrict__ lnOg,
                       const float* __restrict__ lnOb,
                       const float* __restrict__ rbuf,
                       float* __restrict__ dst) {
  const int lane = threadIdx.x & 63;
  const int unit = blockIdx.x * 4 + (threadIdx.x >> 6);  // b*NN + n
  const int b = unit >> 11;
  const int n = unit & (NN - 1);

  float kv[THH];
#pragma unroll
  for (int s = 0; s < THH; ++s)
    kv[s] = states[(((size_t)b * THH + s) * NN + n) * DHD + lane];
  const float go = lnOg[lane], bo = lnOb[lane];

#pragma unroll
  for (int tt = 0; tt < KTT; ++tt) {
    const size_t oi = (((size_t)b * KTT + tt) * NN + n) * DHD + lane;
    const float gval = g[oi];
    float mean = wsum64(gval) * (1.f / 64.f);
    float dv = gval - mean;
    float var = wsum64(dv * dv) * (1.f / 64.f);
    float q = dv * (1.f / sqrtf(var + 1e-5f)) * go + bo;
    float sc[THH];
#pragma unroll
    for (int s = 0; s < THH; ++s) sc[s] = hsum16(q * kv[s]) * 0.25f;
    float mx = sc[0];
#pragma unroll
    for (int s = 1; s < THH; ++s) mx = fmaxf(mx, sc[s]);
    float sum = 0.f;
#pragma unroll
    for (int s = 0; s < THH; ++s) { sc[s] = __expf(sc[s] - mx); sum += sc[s]; }
    float o = 0.f;
#pragma unroll
    for (int s = 0; s < THH; ++s) o += sc[s] * kv[s];
    o /= sum;
    const float val = gval + o;
    if (MODE == 0) {
      dst[oi] = 1.f / (1.f + __expf(-val));
    } else {
      const float hc = tanhf(val);
      const float stl =
          states[(((size_t)b * THH + (THH - KTT) + tt) * NN + n) * DHD + lane];
      const float rr = rbuf[oi];
      dst[oi] = rr * stl + (1.f - rr) * hc;
    }
  }
}

extern "C" void kernel_launch(void* const* d_in, const int* in_sizes, int n_in,
                              void* d_out, int out_size, void* d_ws, size_t ws_size,
                              hipStream_t stream) {
  const float* x        = (const float*)d_in[0];
  const float* states   = (const float*)d_in[1];
  const float* node_emb = (const float*)d_in[2];
  const float* time_emb = (const float*)d_in[3];

  float* ws  = (float*)d_ws;
  float* emb = ws;                                  //  786432 f
  float* Axb = emb + (size_t)BT * NN * DEE;         // 3145728 f
  float* gb  = Axb + (size_t)BT * NN * CC;          // 2097152 f
  float* zb  = gb  + (size_t)BT * NN * DHD;         // 2097152 f
  float* rb  = zb  + (size_t)BT * NN * DHD;         // 2097152 f
  float* outp = (float*)d_out;

  struct Gate { const float *W, *bias, *lAg, *lAb, *lOg, *lOb; };
  auto G = [&](int i) {
    return Gate{(const float*)d_in[i],     (const float*)d_in[i + 1],
                (const float*)d_in[i + 2], (const float*)d_in[i + 3],
                (const float*)d_in[i + 4], (const float*)d_in[i + 5]};
  };
  Gate gz = G(4), gr = G(10), gu = G(16);

  dim3 gridF(NN / RT, BT);
  const int gridE = BT * NN / 256;
  const int gridA = BB * NN / 4;

  // ---- gate z ----
  k_emb<<<gridE, 256, 0, stream>>>(node_emb, time_emb, gz.lAg, gz.lAb, emb);
  k_flash<0><<<gridF, 256, 0, stream>>>(emb, x, states, nullptr, Axb);
  k_nodemm<0><<<NN, 256, 0, stream>>>(x, states, nullptr, Axb, node_emb,
                                      time_emb, gz.W, gz.bias, gb);
  k_attn<0><<<gridA, 256, 0, stream>>>(gb, states, gz.lOg, gz.lOb, nullptr, zb);
  // ---- gate r ----
  k_emb<<<gridE, 256, 0, stream>>>(node_emb, time_emb, gr.lAg, gr.lAb, emb);
  k_flash<0><<<gridF, 256, 0, stream>>>(emb, x, states, nullptr, Axb);
  k_nodemm<0><<<NN, 256, 0, stream>>>(x, states, nullptr, Axb, node_emb,
                                      time_emb, gr.W, gr.bias, gb);
  k_attn<0><<<gridA, 256, 0, stream>>>(gb, states, gr.lOg, gr.lOb, nullptr, rb);
  // ---- gate u + final gate combine ----
  k_emb<<<gridE, 256, 0, stream>>>(node_emb, time_emb, gu.lAg, gu.lAb, emb);
  k_flash<1><<<gridF, 256, 0, stream>>>(emb, x, states, zb, Axb);
  k_nodemm<1><<<NN, 256, 0, stream>>>(x, states, zb, Axb, node_emb, time_emb,
                                      gu.W, gu.bias, gb);
  k_attn<1><<<gridA, 256, 0, stream>>>(gb, states, gu.lOg, gu.lOb, rb, outp);
}

// Round 2
// 1314.040 us; speedup vs baseline: 1.8922x; 1.8922x over previous
//
#include <hip/hip_runtime.h>
#include <math.h>

#define BB  8
#define KTT 2
#define THH 12
#define NN  2048
#define DII 32
#define DHD 64
#define DEE 24
#define CC  96
#define BT  16      // BB*KTT
#define RT  64      // row tile
#define MT  64      // m tile

typedef __attribute__((ext_vector_type(8))) short short8;   // 8 bf16 = 4 VGPRs
typedef __attribute__((ext_vector_type(4))) float f32x4;

#define MFMA16(a, b, c) __builtin_amdgcn_mfma_f32_16x16x32_bf16(a, b, c, 0, 0, 0)

__device__ __forceinline__ unsigned short f2bf(float f) {
  unsigned u = __builtin_bit_cast(unsigned, f);
  u += 0x7FFFu + ((u >> 16) & 1u);
  return (unsigned short)(u >> 16);
}
__device__ __forceinline__ float bf2f(unsigned short h) {
  return __builtin_bit_cast(float, ((unsigned)h) << 16);
}
__device__ __forceinline__ unsigned pack2(float a, float b) {
  return (unsigned)f2bf(a) | ((unsigned)f2bf(b) << 16);
}

// ---- emb = LN(node_emb + time_emb)*g + b (eps 1e-12), split to bf16 hi/lo ----
// Output rows of 32 ushorts (k=24..31 zero-padded) for direct MFMA fragment use.
__global__ void k_emb(const float* __restrict__ node_emb,
                      const float* __restrict__ time_emb,
                      const float* __restrict__ gA,
                      const float* __restrict__ bA,
                      unsigned* __restrict__ emb_hi,
                      unsigned* __restrict__ emb_lo) {
  int idx = blockIdx.x * 256 + threadIdx.x;   // bt*NN + n
  int n  = idx & (NN - 1);
  int bt = idx >> 11;
  float v[DEE];
  float mean = 0.f;
#pragma unroll
  for (int d = 0; d < DEE; ++d) {
    v[d] = node_emb[n * DEE + d] + time_emb[bt * DEE + d];
    mean += v[d];
  }
  mean *= (1.f / DEE);
  float var = 0.f;
#pragma unroll
  for (int d = 0; d < DEE; ++d) { float u = v[d] - mean; var += u * u; }
  var *= (1.f / DEE);
  float inv = 1.f / sqrtf(var + 1e-12f);
  unsigned hi[16], lo[16];
#pragma unroll
  for (int q = 0; q < 12; ++q) {
    float e0 = (v[2*q]   - mean) * inv * gA[2*q]   + bA[2*q];
    float e1 = (v[2*q+1] - mean) * inv * gA[2*q+1] + bA[2*q+1];
    unsigned short h0 = f2bf(e0), h1 = f2bf(e1);
    float l0 = e0 - bf2f(h0), l1 = e1 - bf2f(h1);
    hi[q] = (unsigned)h0 | ((unsigned)h1 << 16);
    lo[q] = pack2(l0, l1);
  }
#pragma unroll
  for (int q = 12; q < 16; ++q) { hi[q] = 0u; lo[q] = 0u; }
  unsigned* dh = emb_hi + (size_t)idx * 16;
  unsigned* dl = emb_lo + (size_t)idx * 16;
#pragma unroll
  for (int q4 = 0; q4 < 4; ++q4) {
    ((uint4*)dh)[q4] = make_uint4(hi[4*q4], hi[4*q4+1], hi[4*q4+2], hi[4*q4+3]);
    ((uint4*)dl)[q4] = make_uint4(lo[4*q4], lo[4*q4+1], lo[4*q4+2], lo[4*q4+3]);
  }
}

// ---------------- fused graph attention via MFMA ----------------------------
// Ax(bf16) = softmax(emb embT) @ concat(x, state[*z]) ; per block: 64 rows, one bt
template <int MODE>
__global__ __launch_bounds__(256, 3) void k_flash(
    const unsigned* __restrict__ emb_hi, const unsigned* __restrict__ emb_lo,
    const float* __restrict__ x, const float* __restrict__ states,
    const float* __restrict__ zbuf, unsigned short* __restrict__ Ax) {
  __shared__ unsigned short s_er_hi[RT * 40];   // [r][k] stride 40 (80B, 16B-aligned)
  __shared__ unsigned short s_er_lo[RT * 40];
  __shared__ unsigned short s_em_hi[MT * 40];
  __shared__ unsigned short s_em_lo[MT * 40];
  __shared__ unsigned short s_xt[2 * 6 * 64 * 8];  // fragment-ready [kc][nt][lane][8]
  __shared__ unsigned short s_p[RT * 72];          // [r][m] stride 72 (144B)

  const int t = threadIdx.x;
  const int w = t >> 6, l = t & 63;
  const int lane_lo = l & 15, lane_hi = l >> 4;
  const int k0 = lane_hi * 8;
  const int bt = blockIdx.y, b = bt >> 1, tt = bt & 1;
  const int rbase = blockIdx.x * RT;

  // ---- stage er (once per block) ----
  {
    const unsigned* sh = emb_hi + ((size_t)bt * NN + rbase) * 16;
    const unsigned* sl = emb_lo + ((size_t)bt * NN + rbase) * 16;
#pragma unroll
    for (int q = 0; q < 4; ++q) {
      int e = t + 256 * q;        // 1024 uints
      int node = e >> 4, off = e & 15;
      ((unsigned*)s_er_hi)[node * 20 + off] = sh[e];
      ((unsigned*)s_er_lo)[node * 20 + off] = sl[e];
    }
  }
  __syncthreads();
  const short8 a_hi = *(const short8*)&s_er_hi[(w * 16 + lane_lo) * 40 + k0];
  const short8 a_lo = *(const short8*)&s_er_lo[(w * 16 + lane_lo) * 40 + k0];

  float m_run[4], l_run[4];
#pragma unroll
  for (int i = 0; i < 4; ++i) { m_run[i] = -1e30f; l_run[i] = 0.f; }
  f32x4 acc[6];
#pragma unroll
  for (int j = 0; j < 6; ++j) acc[j] = (f32x4){0.f, 0.f, 0.f, 0.f};

  for (int mt = 0; mt < NN / MT; ++mt) {
    const int mbase = mt * MT;
    __syncthreads();   // previous-tile readers of s_em / s_xt are done
    // ---- stage em tile ----
    {
      const unsigned* sh = emb_hi + ((size_t)bt * NN + mbase) * 16;
      const unsigned* sl = emb_lo + ((size_t)bt * NN + mbase) * 16;
#pragma unroll
      for (int q = 0; q < 4; ++q) {
        int e = t + 256 * q;
        int node = e >> 4, off = e & 15;
        ((unsigned*)s_em_hi)[node * 20 + off] = sh[e];
        ((unsigned*)s_em_lo)[node * 20 + off] = sl[e];
      }
    }
    // ---- stage xin tile, transposed into fragment-ready layout ----
    {
#pragma unroll
      for (int q = 0; q < 4; ++q) {       // x part: 64m x 32c, 2 m per thread
        int e = t + 256 * q;
        int m2 = e >> 5, c = e & 31;
        int m = m2 * 2;
        const float* xp = &x[((size_t)bt * NN + mbase + m) * DII + c];
        float v0 = xp[0], v1 = xp[DII];
        int kc = m >> 5, g = (m >> 3) & 3, j = m & 7;
        int nt = c >> 4, ll = c & 15;
        ((unsigned*)s_xt)[((kc * 6 + nt) * 64 + (ll + g * 16)) * 4 + (j >> 1)] =
            pack2(v0, v1);
      }
#pragma unroll
      for (int q = 0; q < 8; ++q) {       // state part: 64m x 64d
        int e = t + 256 * q;
        int m2 = e >> 6, d = e & 63;
        int m = m2 * 2;
        size_t sidx = (((size_t)b * THH + (THH - KTT) + tt) * NN + mbase + m) * DHD + d;
        float v0 = states[sidx], v1 = states[sidx + DHD];
        if (MODE == 1) {
          size_t zidx = ((size_t)bt * NN + mbase + m) * DHD + d;
          v0 *= zbuf[zidx];
          v1 *= zbuf[zidx + DHD];
        }
        int c = 32 + d;
        int kc = m >> 5, g = (m >> 3) & 3, j = m & 7;
        int nt = c >> 4, ll = c & 15;
        ((unsigned*)s_xt)[((kc * 6 + nt) * 64 + (ll + g * 16)) * 4 + (j >> 1)] =
            pack2(v0, v1);
      }
    }
    __syncthreads();
    // ---- scores: S = Ehi*Bhi + Ehi*Blo + Elo*Bhi  (fp32-quality) ----
    f32x4 sc[4];
#pragma unroll
    for (int nt = 0; nt < 4; ++nt) {
      const short8 b_hi = *(const short8*)&s_em_hi[(nt * 16 + lane_lo) * 40 + k0];
      const short8 b_lo = *(const short8*)&s_em_lo[(nt * 16 + lane_lo) * 40 + k0];
      f32x4 c0 = (f32x4){0.f, 0.f, 0.f, 0.f};
      c0 = MFMA16(a_hi, b_hi, c0);
      c0 = MFMA16(a_hi, b_lo, c0);
      c0 = MFMA16(a_lo, b_hi, c0);
      sc[nt] = c0;
    }
    // ---- online softmax in registers (rows = lane_hi*4 + i) ----
    float alpha[4], nm[4];
#pragma unroll
    for (int i = 0; i < 4; ++i) {
      float mx = fmaxf(fmaxf(sc[0][i], sc[1][i]), fmaxf(sc[2][i], sc[3][i]));
      mx = fmaxf(mx, __shfl_xor(mx, 1, 64));
      mx = fmaxf(mx, __shfl_xor(mx, 2, 64));
      mx = fmaxf(mx, __shfl_xor(mx, 4, 64));
      mx = fmaxf(mx, __shfl_xor(mx, 8, 64));
      nm[i] = fmaxf(m_run[i], mx);
      alpha[i] = __expf(m_run[i] - nm[i]);
      m_run[i] = nm[i];
    }
    float p[4][4];
    float rs[4];
#pragma unroll
    for (int i = 0; i < 4; ++i) rs[i] = 0.f;
#pragma unroll
    for (int nt = 0; nt < 4; ++nt)
#pragma unroll
      for (int i = 0; i < 4; ++i) {
        float pv = __expf(sc[nt][i] - nm[i]);
        p[nt][i] = pv;
        rs[i] += pv;
      }
#pragma unroll
    for (int i = 0; i < 4; ++i) {
      float s = rs[i];
      s += __shfl_xor(s, 1, 64);
      s += __shfl_xor(s, 2, 64);
      s += __shfl_xor(s, 4, 64);
      s += __shfl_xor(s, 8, 64);
      l_run[i] = l_run[i] * alpha[i] + s;
    }
    // ---- write P (bf16) to wave-private LDS rows; no barrier needed ----
#pragma unroll
    for (int nt = 0; nt < 4; ++nt)
#pragma unroll
      for (int i = 0; i < 4; ++i)
        s_p[(w * 16 + lane_hi * 4 + i) * 72 + nt * 16 + lane_lo] = f2bf(p[nt][i]);
    // ---- rescale accumulators ----
#pragma unroll
    for (int j = 0; j < 6; ++j)
#pragma unroll
      for (int i = 0; i < 4; ++i) acc[j][i] *= alpha[i];
    // ---- PV: O += P @ xin ----
    const short8 pa0 = *(const short8*)&s_p[(w * 16 + lane_lo) * 72 + k0];
    const short8 pa1 = *(const short8*)&s_p[(w * 16 + lane_lo) * 72 + 32 + k0];
#pragma unroll
    for (int nt2 = 0; nt2 < 6; ++nt2) {
      const short8 xb0 = *(const short8*)&s_xt[((0 * 6 + nt2) * 64 + l) * 8];
      const short8 xb1 = *(const short8*)&s_xt[((1 * 6 + nt2) * 64 + l) * 8];
      acc[nt2] = MFMA16(pa0, xb0, acc[nt2]);
      acc[nt2] = MFMA16(pa1, xb1, acc[nt2]);
    }
  }
  // ---- epilogue: normalize, write bf16 ----
  float invl[4];
#pragma unroll
  for (int i = 0; i < 4; ++i) invl[i] = 1.f / l_run[i];
#pragma unroll
  for (int nt2 = 0; nt2 < 6; ++nt2)
#pragma unroll
    for (int i = 0; i < 4; ++i) {
      size_t o = ((size_t)bt * NN + rbase + w * 16 + lane_hi * 4 + i) * CC +
                 nt2 * 16 + lane_lo;
      Ax[o] = f2bf(acc[nt2][i] * invl[i]);
    }
}

// ------------- per-node weight matmul: g = xg @ (node_emb@Wp) + bias ---------
template <int MODE>
__global__ __launch_bounds__(256, 2) void k_nodemm(
    const float* __restrict__ x, const float* __restrict__ states,
    const float* __restrict__ zbuf, const unsigned short* __restrict__ Ax,
    const float* __restrict__ node_emb, const float* __restrict__ time_emb,
    const float* __restrict__ Wp, const float* __restrict__ bp,
    float* __restrict__ g) {
  __shared__ alignas(16) float s_W[192 * 64];   // [ki][o]
  __shared__ float s_xg[BT * 193];              // [bt][0..191] padded
  __shared__ float s_ne[DEE];
  __shared__ float s_te[BT * DEE];

  const int t = threadIdx.x;
  const int n = blockIdx.x;

  if (t < DEE) s_ne[t] = node_emb[n * DEE + t];
  for (int e = t; e < BT * DEE; e += 256) s_te[e] = time_emb[e];
  __syncthreads();

  float ne[DEE];
#pragma unroll
  for (int d = 0; d < DEE; ++d) ne[d] = s_ne[d];

  for (int k2 = 0; k2 < 48; ++k2) {
    int j = t + 256 * k2;
    float a = 0.f;
#pragma unroll
    for (int d = 0; d < DEE; ++d) a += ne[d] * Wp[(size_t)d * 12288 + j];
    s_W[j] = a;
  }

  for (int e = t; e < BT * 192; e += 256) {
    int btv = e / 192, c = e - btv * 192;
    float v;
    if (c < DII) {
      v = x[((size_t)btv * NN + n) * DII + c];
    } else if (c < CC) {
      v = states[(((size_t)(btv >> 1) * THH + (THH - KTT) + (btv & 1)) * NN + n) * DHD + (c - DII)];
      if (MODE == 1) v *= zbuf[((size_t)btv * NN + n) * DHD + (c - DII)];
    } else {
      v = bf2f(Ax[((size_t)btv * NN + n) * CC + (c - CC)]);
    }
    s_xg[btv * 193 + c] = v;
  }
  __syncthreads();

  const int btv = t >> 4;          // 16 bt rows
  const int o0  = (t & 15) * 4;    // 64 outputs in 4-wide chunks
  float y[4];
#pragma unroll
  for (int q = 0; q < 4; ++q) y[q] = 0.f;
#pragma unroll
  for (int d = 0; d < DEE; ++d) {
    float te = s_te[btv * DEE + d];
#pragma unroll
    for (int q = 0; q < 4; ++q) y[q] += te * bp[d * DHD + o0 + q];
  }
  const float* xr = &s_xg[btv * 193];
  for (int i = 0; i < 192; ++i) {
    float xv = xr[i];
    const float4 w4 = *(const float4*)&s_W[i * 64 + o0];
    y[0] += xv * w4.x; y[1] += xv * w4.y; y[2] += xv * w4.z; y[3] += xv * w4.w;
  }
  float* dst = &g[((size_t)btv * NN + n) * DHD + o0];
#pragma unroll
  for (int q = 0; q < 4; ++q) dst[q] = y[q];
}

// --------------------- LN + tiny MHA + activation / gate ---------------------
__device__ __forceinline__ float wsum64(float v) {
#pragma unroll
  for (int off = 32; off > 0; off >>= 1) v += __shfl_xor(v, off, 64);
  return v;
}
__device__ __forceinline__ float hsum16(float v) {
  v += __shfl_xor(v, 8, 64);
  v += __shfl_xor(v, 4, 64);
  v += __shfl_xor(v, 2, 64);
  v += __shfl_xor(v, 1, 64);
  return v;
}

// MODE 0: dst = sigmoid(g + mha)  ; MODE 1: dst = r*state + (1-r)*tanh(g + mha)
template <int MODE>
__global__ void k_attn(const float* __restrict__ g,
                       const float* __restrict__ states,
                       const float* __restrict__ lnOg,
                       const float* __restrict__ lnOb,
                       const float* __restrict__ rbuf,
                       float* __restrict__ dst) {
  const int lane = threadIdx.x & 63;
  const int unit = blockIdx.x * 4 + (threadIdx.x >> 6);  // b*NN + n
  const int b = unit >> 11;
  const int n = unit & (NN - 1);

  float kv[THH];
#pragma unroll
  for (int s = 0; s < THH; ++s)
    kv[s] = states[(((size_t)b * THH + s) * NN + n) * DHD + lane];
  const float go = lnOg[lane], bo = lnOb[lane];

#pragma unroll
  for (int tt = 0; tt < KTT; ++tt) {
    const size_t oi = (((size_t)b * KTT + tt) * NN + n) * DHD + lane;
    const float gval = g[oi];
    float mean = wsum64(gval) * (1.f / 64.f);
    float dv = gval - mean;
    float var = wsum64(dv * dv) * (1.f / 64.f);
    float q = dv * (1.f / sqrtf(var + 1e-5f)) * go + bo;
    float sc[THH];
#pragma unroll
    for (int s = 0; s < THH; ++s) sc[s] = hsum16(q * kv[s]) * 0.25f;
    float mx = sc[0];
#pragma unroll
    for (int s = 1; s < THH; ++s) mx = fmaxf(mx, sc[s]);
    float sum = 0.f;
#pragma unroll
    for (int s = 0; s < THH; ++s) { sc[s] = __expf(sc[s] - mx); sum += sc[s]; }
    float o = 0.f;
#pragma unroll
    for (int s = 0; s < THH; ++s) o += sc[s] * kv[s];
    o /= sum;
    const float val = gval + o;
    if (MODE == 0) {
      dst[oi] = 1.f / (1.f + __expf(-val));
    } else {
      const float hc = tanhf(val);
      const float stl =
          states[(((size_t)b * THH + (THH - KTT) + tt) * NN + n) * DHD + lane];
      const float rr = rbuf[oi];
      dst[oi] = rr * stl + (1.f - rr) * hc;
    }
  }
}

extern "C" void kernel_launch(void* const* d_in, const int* in_sizes, int n_in,
                              void* d_out, int out_size, void* d_ws, size_t ws_size,
                              hipStream_t stream) {
  const float* x        = (const float*)d_in[0];
  const float* states   = (const float*)d_in[1];
  const float* node_emb = (const float*)d_in[2];
  const float* time_emb = (const float*)d_in[3];

  // workspace layout (bytes): embHi 2M | embLo 2M | Ax(bf16) 6M | g 8M | z 8M | r 8M
  unsigned char* wsb = (unsigned char*)d_ws;
  unsigned*       embHi = (unsigned*)wsb;                         // BT*NN*16 uints
  unsigned*       embLo = (unsigned*)(wsb + 2097152);
  unsigned short* Axb   = (unsigned short*)(wsb + 4194304);       // BT*NN*96 bf16
  float*          gb    = (float*)(wsb + 10485760);
  float*          zb    = (float*)(wsb + 18874368);
  float*          rb    = (float*)(wsb + 27262976);
  float* outp = (float*)d_out;

  struct Gate { const float *W, *bias, *lAg, *lAb, *lOg, *lOb; };
  auto G = [&](int i) {
    return Gate{(const float*)d_in[i],     (const float*)d_in[i + 1],
                (const float*)d_in[i + 2], (const float*)d_in[i + 3],
                (const float*)d_in[i + 4], (const float*)d_in[i + 5]};
  };
  Gate gz = G(4), gr = G(10), gu = G(16);

  dim3 gridF(NN / RT, BT);
  const int gridE = BT * NN / 256;
  const int gridA = BB * NN / 4;

  // ---- gate z ----
  k_emb<<<gridE, 256, 0, stream>>>(node_emb, time_emb, gz.lAg, gz.lAb, embHi, embLo);
  k_flash<0><<<gridF, 256, 0, stream>>>(embHi, embLo, x, states, nullptr, Axb);
  k_nodemm<0><<<NN, 256, 0, stream>>>(x, states, nullptr, Axb, node_emb,
                                      time_emb, gz.W, gz.bias, gb);
  k_attn<0><<<gridA, 256, 0, stream>>>(gb, states, gz.lOg, gz.lOb, nullptr, zb);
  // ---- gate r ----
  k_emb<<<gridE, 256, 0, stream>>>(node_emb, time_emb, gr.lAg, gr.lAb, embHi, embLo);
  k_flash<0><<<gridF, 256, 0, stream>>>(embHi, embLo, x, states, nullptr, Axb);
  k_nodemm<0><<<NN, 256, 0, stream>>>(x, states, nullptr, Axb, node_emb,
                                      time_emb, gr.W, gr.bias, gb);
  k_attn<0><<<gridA, 256, 0, stream>>>(gb, states, gr.lOg, gr.lOb, nullptr, rb);
  // ---- gate u + final gate combine ----
  k_emb<<<gridE, 256, 0, stream>>>(node_emb, time_emb, gu.lAg, gu.lAb, embHi, embLo);
  k_flash<1><<<gridF, 256, 0, stream>>>(embHi, embLo, x, states, zb, Axb);
  k_nodemm<1><<<NN, 256, 0, stream>>>(x, states, zb, Axb, node_emb, time_emb,
                                      gu.W, gu.bias, gb);
  k_attn<1><<<gridA, 256, 0, stream>>>(gb, states, gu.lOg, gu.lOb, rb, outp);
}

// Round 3
// 826.999 us; speedup vs baseline: 3.0065x; 1.5889x over previous
//
#include <hip/hip_runtime.h>
#include <math.h>

#define BB  8
#define KTT 2
#define THH 12
#define NN  2048
#define DII 32
#define DHD 64
#define DEE 24
#define CC  96
#define BT  16      // BB*KTT
#define RT  64      // row tile
#define MT  64      // m tile

typedef __attribute__((ext_vector_type(8))) short short8;   // 8 bf16 = 4 VGPRs
typedef __attribute__((ext_vector_type(4))) float f32x4;

#define MFMA16(a, b, c) __builtin_amdgcn_mfma_f32_16x16x32_bf16(a, b, c, 0, 0, 0)

__device__ __forceinline__ unsigned short f2bf(float f) {
  unsigned u = __builtin_bit_cast(unsigned, f);
  u += 0x7FFFu + ((u >> 16) & 1u);
  return (unsigned short)(u >> 16);
}
__device__ __forceinline__ float bf2f(unsigned short h) {
  return __builtin_bit_cast(float, ((unsigned)h) << 16);
}
__device__ __forceinline__ unsigned pack2(float a, float b) {
  return (unsigned)f2bf(a) | ((unsigned)f2bf(b) << 16);
}

// ---- LN(node_emb + time_emb)*g + b (eps 1e-12) -> bf16 hi/lo, two gates ----
__global__ void k_emb2(const float* __restrict__ node_emb,
                       const float* __restrict__ time_emb,
                       const float* __restrict__ gZ, const float* __restrict__ bZ,
                       const float* __restrict__ gR, const float* __restrict__ bR,
                       unsigned* __restrict__ ehZ, unsigned* __restrict__ elZ,
                       unsigned* __restrict__ ehR, unsigned* __restrict__ elR) {
  int idx = blockIdx.x * 256 + threadIdx.x;   // bt*NN + n
  int n  = idx & (NN - 1);
  int bt = idx >> 11;
  float v[DEE];
  float mean = 0.f;
#pragma unroll
  for (int d = 0; d < DEE; ++d) {
    v[d] = node_emb[n * DEE + d] + time_emb[bt * DEE + d];
    mean += v[d];
  }
  mean *= (1.f / DEE);
  float var = 0.f;
#pragma unroll
  for (int d = 0; d < DEE; ++d) { float u = v[d] - mean; var += u * u; }
  var *= (1.f / DEE);
  float inv = 1.f / sqrtf(var + 1e-12f);
#pragma unroll
  for (int gate = 0; gate < 2; ++gate) {
    const float* ga = gate ? gR : gZ;
    const float* ba = gate ? bR : bZ;
    unsigned* dh = (gate ? ehR : ehZ) + (size_t)idx * 16;
    unsigned* dl = (gate ? elR : elZ) + (size_t)idx * 16;
    unsigned hi[16], lo[16];
#pragma unroll
    for (int q = 0; q < 12; ++q) {
      float e0 = (v[2*q]   - mean) * inv * ga[2*q]   + ba[2*q];
      float e1 = (v[2*q+1] - mean) * inv * ga[2*q+1] + ba[2*q+1];
      unsigned short h0 = f2bf(e0), h1 = f2bf(e1);
      hi[q] = (unsigned)h0 | ((unsigned)h1 << 16);
      lo[q] = pack2(e0 - bf2f(h0), e1 - bf2f(h1));
    }
#pragma unroll
    for (int q = 12; q < 16; ++q) { hi[q] = 0u; lo[q] = 0u; }
#pragma unroll
    for (int q4 = 0; q4 < 4; ++q4) {
      ((uint4*)dh)[q4] = make_uint4(hi[4*q4], hi[4*q4+1], hi[4*q4+2], hi[4*q4+3]);
      ((uint4*)dl)[q4] = make_uint4(lo[4*q4], lo[4*q4+1], lo[4*q4+2], lo[4*q4+3]);
    }
  }
}

// single-gate variant (for u)
__global__ void k_emb(const float* __restrict__ node_emb,
                      const float* __restrict__ time_emb,
                      const float* __restrict__ gA, const float* __restrict__ bA,
                      unsigned* __restrict__ emb_hi, unsigned* __restrict__ emb_lo) {
  int idx = blockIdx.x * 256 + threadIdx.x;
  int n  = idx & (NN - 1);
  int bt = idx >> 11;
  float v[DEE];
  float mean = 0.f;
#pragma unroll
  for (int d = 0; d < DEE; ++d) {
    v[d] = node_emb[n * DEE + d] + time_emb[bt * DEE + d];
    mean += v[d];
  }
  mean *= (1.f / DEE);
  float var = 0.f;
#pragma unroll
  for (int d = 0; d < DEE; ++d) { float u = v[d] - mean; var += u * u; }
  var *= (1.f / DEE);
  float inv = 1.f / sqrtf(var + 1e-12f);
  unsigned hi[16], lo[16];
#pragma unroll
  for (int q = 0; q < 12; ++q) {
    float e0 = (v[2*q]   - mean) * inv * gA[2*q]   + bA[2*q];
    float e1 = (v[2*q+1] - mean) * inv * gA[2*q+1] + bA[2*q+1];
    unsigned short h0 = f2bf(e0), h1 = f2bf(e1);
    hi[q] = (unsigned)h0 | ((unsigned)h1 << 16);
    lo[q] = pack2(e0 - bf2f(h0), e1 - bf2f(h1));
  }
#pragma unroll
  for (int q = 12; q < 16; ++q) { hi[q] = 0u; lo[q] = 0u; }
  unsigned* dh = emb_hi + (size_t)idx * 16;
  unsigned* dl = emb_lo + (size_t)idx * 16;
#pragma unroll
  for (int q4 = 0; q4 < 4; ++q4) {
    ((uint4*)dh)[q4] = make_uint4(hi[4*q4], hi[4*q4+1], hi[4*q4+2], hi[4*q4+3]);
    ((uint4*)dl)[q4] = make_uint4(lo[4*q4], lo[4*q4+1], lo[4*q4+2], lo[4*q4+3]);
  }
}

// XCD-aware block swizzle: each XCD (id = L%8) sees only bt = {2j, 2j+1}
__device__ __forceinline__ void swz(int L, int& bt, int& rbase) {
  bt = (L & 7) * 2 + ((L >> 3) & 1);
  rbase = (L >> 4) * RT;
}

// ---------------- fused graph attention, z+r merged ----------------------
__global__ __launch_bounds__(256, 2) void k_flash_zr(
    const unsigned* __restrict__ ehZ, const unsigned* __restrict__ elZ,
    const unsigned* __restrict__ ehR, const unsigned* __restrict__ elR,
    const float* __restrict__ x, const float* __restrict__ states,
    unsigned short* __restrict__ AxZ, unsigned short* __restrict__ AxR) {
  __shared__ unsigned short s_er[2][2][RT * 40];   // [gate][hi/lo][r][k]
  __shared__ unsigned short s_em[2][2][MT * 40];
  __shared__ unsigned short s_xt[2 * 6 * 64 * 8];  // [kc][nt][lane][8]
  __shared__ unsigned short s_p[2][RT * 72];

  const int t = threadIdx.x;
  const int w = t >> 6, l = t & 63;
  const int lane_lo = l & 15, lane_hi = l >> 4;
  const int k0 = lane_hi * 8;
  int bt, rbase; swz(blockIdx.x, bt, rbase);
  const int b = bt >> 1, tt = bt & 1;

  const unsigned* eh[2] = {ehZ, ehR};
  const unsigned* el[2] = {elZ, elR};

  // ---- stage er for both gates ----
#pragma unroll
  for (int g = 0; g < 2; ++g) {
    const unsigned* sh = eh[g] + ((size_t)bt * NN + rbase) * 16;
    const unsigned* sl = el[g] + ((size_t)bt * NN + rbase) * 16;
#pragma unroll
    for (int q = 0; q < 4; ++q) {
      int e = t + 256 * q;
      int node = e >> 4, off = e & 15;
      ((unsigned*)s_er[g][0])[node * 20 + off] = sh[e];
      ((unsigned*)s_er[g][1])[node * 20 + off] = sl[e];
    }
  }

  // ---- prefetch registers ----
  unsigned pem[2][2][4];
  unsigned pxw[4], psw[8];
  auto preload = [&](int mbase) {
#pragma unroll
    for (int g = 0; g < 2; ++g) {
      const unsigned* sh = eh[g] + ((size_t)bt * NN + mbase) * 16;
      const unsigned* sl = el[g] + ((size_t)bt * NN + mbase) * 16;
#pragma unroll
      for (int q = 0; q < 4; ++q) {
        int e = t + 256 * q;
        pem[g][0][q] = sh[e];
        pem[g][1][q] = sl[e];
      }
    }
#pragma unroll
    for (int q = 0; q < 4; ++q) {
      int e = t + 256 * q;
      int m = (e >> 5) * 2, c = e & 31;
      const float* xp = &x[((size_t)bt * NN + mbase + m) * DII + c];
      pxw[q] = pack2(xp[0], xp[DII]);
    }
#pragma unroll
    for (int q = 0; q < 8; ++q) {
      int e = t + 256 * q;
      int m = (e >> 6) * 2, d = e & 63;
      size_t sidx = (((size_t)b * THH + (THH - KTT) + tt) * NN + mbase + m) * DHD + d;
      psw[q] = pack2(states[sidx], states[sidx + DHD]);
    }
  };
  preload(0);
  __syncthreads();

  short8 a_hi[2], a_lo[2];
#pragma unroll
  for (int g = 0; g < 2; ++g) {
    a_hi[g] = *(const short8*)&s_er[g][0][(w * 16 + lane_lo) * 40 + k0];
    a_lo[g] = *(const short8*)&s_er[g][1][(w * 16 + lane_lo) * 40 + k0];
  }

  float m_run[2][4], l_run[2][4];
#pragma unroll
  for (int g = 0; g < 2; ++g)
#pragma unroll
    for (int i = 0; i < 4; ++i) { m_run[g][i] = -1e30f; l_run[g][i] = 0.f; }
  f32x4 acc[2][6];
#pragma unroll
  for (int g = 0; g < 2; ++g)
#pragma unroll
    for (int j = 0; j < 6; ++j) acc[g][j] = (f32x4){0.f, 0.f, 0.f, 0.f};

  for (int mt = 0; mt < NN / MT; ++mt) {
    __syncthreads();
    // ---- write prefetched regs -> LDS ----
#pragma unroll
    for (int g = 0; g < 2; ++g)
#pragma unroll
      for (int q = 0; q < 4; ++q) {
        int e = t + 256 * q;
        int node = e >> 4, off = e & 15;
        ((unsigned*)s_em[g][0])[node * 20 + off] = pem[g][0][q];
        ((unsigned*)s_em[g][1])[node * 20 + off] = pem[g][1][q];
      }
#pragma unroll
    for (int q = 0; q < 4; ++q) {
      int e = t + 256 * q;
      int m2 = e >> 5, c = e & 31;
      int kc = m2 >> 4, g2 = (m2 >> 2) & 3, wd = m2 & 3;
      int nt = c >> 4, ll = c & 15;
      ((unsigned*)s_xt)[((kc * 6 + nt) * 64 + (ll + g2 * 16)) * 4 + wd] = pxw[q];
    }
#pragma unroll
    for (int q = 0; q < 8; ++q) {
      int e = t + 256 * q;
      int m2 = e >> 6, d = e & 63;
      int c = DII + d;
      int kc = m2 >> 4, g2 = (m2 >> 2) & 3, wd = m2 & 3;
      int nt = c >> 4, ll = c & 15;
      ((unsigned*)s_xt)[((kc * 6 + nt) * 64 + (ll + g2 * 16)) * 4 + wd] = psw[q];
    }
    __syncthreads();
    if (mt + 1 < NN / MT) preload((mt + 1) * MT);   // overlap with compute

    // ---- scores for both gates ----
    f32x4 sc[2][4];
#pragma unroll
    for (int g = 0; g < 2; ++g)
#pragma unroll
      for (int nt = 0; nt < 4; ++nt) {
        const short8 b_hi = *(const short8*)&s_em[g][0][(nt * 16 + lane_lo) * 40 + k0];
        const short8 b_lo = *(const short8*)&s_em[g][1][(nt * 16 + lane_lo) * 40 + k0];
        f32x4 c0 = (f32x4){0.f, 0.f, 0.f, 0.f};
        c0 = MFMA16(a_hi[g], b_hi, c0);
        c0 = MFMA16(a_hi[g], b_lo, c0);
        c0 = MFMA16(a_lo[g], b_hi, c0);
        sc[g][nt] = c0;
      }
    // ---- online softmax (per gate) ----
#pragma unroll
    for (int g = 0; g < 2; ++g) {
      float alpha[4], nm[4];
#pragma unroll
      for (int i = 0; i < 4; ++i) {
        float mx = fmaxf(fmaxf(sc[g][0][i], sc[g][1][i]),
                         fmaxf(sc[g][2][i], sc[g][3][i]));
        mx = fmaxf(mx, __shfl_xor(mx, 1, 64));
        mx = fmaxf(mx, __shfl_xor(mx, 2, 64));
        mx = fmaxf(mx, __shfl_xor(mx, 4, 64));
        mx = fmaxf(mx, __shfl_xor(mx, 8, 64));
        nm[i] = fmaxf(m_run[g][i], mx);
        alpha[i] = __expf(m_run[g][i] - nm[i]);
        m_run[g][i] = nm[i];
      }
      float rs[4] = {0.f, 0.f, 0.f, 0.f};
#pragma unroll
      for (int nt = 0; nt < 4; ++nt)
#pragma unroll
        for (int i = 0; i < 4; ++i) {
          float pv = __expf(sc[g][nt][i] - nm[i]);
          s_p[g][(w * 16 + lane_hi * 4 + i) * 72 + nt * 16 + lane_lo] = f2bf(pv);
          rs[i] += pv;
        }
#pragma unroll
      for (int i = 0; i < 4; ++i) {
        float s = rs[i];
        s += __shfl_xor(s, 1, 64);
        s += __shfl_xor(s, 2, 64);
        s += __shfl_xor(s, 4, 64);
        s += __shfl_xor(s, 8, 64);
        l_run[g][i] = l_run[g][i] * alpha[i] + s;
      }
#pragma unroll
      for (int j = 0; j < 6; ++j)
#pragma unroll
        for (int i = 0; i < 4; ++i) acc[g][j][i] *= alpha[i];
    }
    // ---- PV for both gates, sharing xin fragments ----
    const short8 paZ0 = *(const short8*)&s_p[0][(w * 16 + lane_lo) * 72 + k0];
    const short8 paZ1 = *(const short8*)&s_p[0][(w * 16 + lane_lo) * 72 + 32 + k0];
    const short8 paR0 = *(const short8*)&s_p[1][(w * 16 + lane_lo) * 72 + k0];
    const short8 paR1 = *(const short8*)&s_p[1][(w * 16 + lane_lo) * 72 + 32 + k0];
#pragma unroll
    for (int nt2 = 0; nt2 < 6; ++nt2) {
      const short8 xb0 = *(const short8*)&s_xt[((0 * 6 + nt2) * 64 + l) * 8];
      const short8 xb1 = *(const short8*)&s_xt[((1 * 6 + nt2) * 64 + l) * 8];
      acc[0][nt2] = MFMA16(paZ0, xb0, acc[0][nt2]);
      acc[0][nt2] = MFMA16(paZ1, xb1, acc[0][nt2]);
      acc[1][nt2] = MFMA16(paR0, xb0, acc[1][nt2]);
      acc[1][nt2] = MFMA16(paR1, xb1, acc[1][nt2]);
    }
  }
  // ---- epilogue ----
#pragma unroll
  for (int g = 0; g < 2; ++g) {
    unsigned short* Ax = g ? AxR : AxZ;
    float invl[4];
#pragma unroll
    for (int i = 0; i < 4; ++i) invl[i] = 1.f / l_run[g][i];
#pragma unroll
    for (int nt2 = 0; nt2 < 6; ++nt2)
#pragma unroll
      for (int i = 0; i < 4; ++i) {
        size_t o = ((size_t)bt * NN + rbase + w * 16 + lane_hi * 4 + i) * CC +
                   nt2 * 16 + lane_lo;
        Ax[o] = f2bf(acc[g][nt2][i] * invl[i]);
      }
  }
}

// ---------------- single-gate flash (u): xin = concat(x, z*state) ------------
__global__ __launch_bounds__(256, 2) void k_flash_u(
    const unsigned* __restrict__ emb_hi, const unsigned* __restrict__ emb_lo,
    const float* __restrict__ x, const float* __restrict__ states,
    const float* __restrict__ zbuf, unsigned short* __restrict__ Ax) {
  __shared__ unsigned short s_er_hi[RT * 40];
  __shared__ unsigned short s_er_lo[RT * 40];
  __shared__ unsigned short s_em_hi[MT * 40];
  __shared__ unsigned short s_em_lo[MT * 40];
  __shared__ unsigned short s_xt[2 * 6 * 64 * 8];
  __shared__ unsigned short s_p[RT * 72];

  const int t = threadIdx.x;
  const int w = t >> 6, l = t & 63;
  const int lane_lo = l & 15, lane_hi = l >> 4;
  const int k0 = lane_hi * 8;
  int bt, rbase; swz(blockIdx.x, bt, rbase);
  const int b = bt >> 1, tt = bt & 1;

  {
    const unsigned* sh = emb_hi + ((size_t)bt * NN + rbase) * 16;
    const unsigned* sl = emb_lo + ((size_t)bt * NN + rbase) * 16;
#pragma unroll
    for (int q = 0; q < 4; ++q) {
      int e = t + 256 * q;
      int node = e >> 4, off = e & 15;
      ((unsigned*)s_er_hi)[node * 20 + off] = sh[e];
      ((unsigned*)s_er_lo)[node * 20 + off] = sl[e];
    }
  }
  unsigned pemh[4], peml[4], pxw[4], psw[8];
  auto preload = [&](int mbase) {
    const unsigned* sh = emb_hi + ((size_t)bt * NN + mbase) * 16;
    const unsigned* sl = emb_lo + ((size_t)bt * NN + mbase) * 16;
#pragma unroll
    for (int q = 0; q < 4; ++q) {
      int e = t + 256 * q;
      pemh[q] = sh[e];
      peml[q] = sl[e];
    }
#pragma unroll
    for (int q = 0; q < 4; ++q) {
      int e = t + 256 * q;
      int m = (e >> 5) * 2, c = e & 31;
      const float* xp = &x[((size_t)bt * NN + mbase + m) * DII + c];
      pxw[q] = pack2(xp[0], xp[DII]);
    }
#pragma unroll
    for (int q = 0; q < 8; ++q) {
      int e = t + 256 * q;
      int m = (e >> 6) * 2, d = e & 63;
      size_t sidx = (((size_t)b * THH + (THH - KTT) + tt) * NN + mbase + m) * DHD + d;
      size_t zidx = ((size_t)bt * NN + mbase + m) * DHD + d;
      psw[q] = pack2(states[sidx] * zbuf[zidx], states[sidx + DHD] * zbuf[zidx + DHD]);
    }
  };
  preload(0);
  __syncthreads();
  const short8 a_hi = *(const short8*)&s_er_hi[(w * 16 + lane_lo) * 40 + k0];
  const short8 a_lo = *(const short8*)&s_er_lo[(w * 16 + lane_lo) * 40 + k0];

  float m_run[4], l_run[4];
#pragma unroll
  for (int i = 0; i < 4; ++i) { m_run[i] = -1e30f; l_run[i] = 0.f; }
  f32x4 acc[6];
#pragma unroll
  for (int j = 0; j < 6; ++j) acc[j] = (f32x4){0.f, 0.f, 0.f, 0.f};

  for (int mt = 0; mt < NN / MT; ++mt) {
    __syncthreads();
#pragma unroll
    for (int q = 0; q < 4; ++q) {
      int e = t + 256 * q;
      int node = e >> 4, off = e & 15;
      ((unsigned*)s_em_hi)[node * 20 + off] = pemh[q];
      ((unsigned*)s_em_lo)[node * 20 + off] = peml[q];
    }
#pragma unroll
    for (int q = 0; q < 4; ++q) {
      int e = t + 256 * q;
      int m2 = e >> 5, c = e & 31;
      int kc = m2 >> 4, g2 = (m2 >> 2) & 3, wd = m2 & 3;
      int nt = c >> 4, ll = c & 15;
      ((unsigned*)s_xt)[((kc * 6 + nt) * 64 + (ll + g2 * 16)) * 4 + wd] = pxw[q];
    }
#pragma unroll
    for (int q = 0; q < 8; ++q) {
      int e = t + 256 * q;
      int m2 = e >> 6, d = e & 63;
      int c = DII + d;
      int kc = m2 >> 4, g2 = (m2 >> 2) & 3, wd = m2 & 3;
      int nt = c >> 4, ll = c & 15;
      ((unsigned*)s_xt)[((kc * 6 + nt) * 64 + (ll + g2 * 16)) * 4 + wd] = psw[q];
    }
    __syncthreads();
    if (mt + 1 < NN / MT) preload((mt + 1) * MT);

    f32x4 sc[4];
#pragma unroll
    for (int nt = 0; nt < 4; ++nt) {
      const short8 b_hi = *(const short8*)&s_em_hi[(nt * 16 + lane_lo) * 40 + k0];
      const short8 b_lo = *(const short8*)&s_em_lo[(nt * 16 + lane_lo) * 40 + k0];
      f32x4 c0 = (f32x4){0.f, 0.f, 0.f, 0.f};
      c0 = MFMA16(a_hi, b_hi, c0);
      c0 = MFMA16(a_hi, b_lo, c0);
      c0 = MFMA16(a_lo, b_hi, c0);
      sc[nt] = c0;
    }
    float alpha[4], nm[4];
#pragma unroll
    for (int i = 0; i < 4; ++i) {
      float mx = fmaxf(fmaxf(sc[0][i], sc[1][i]), fmaxf(sc[2][i], sc[3][i]));
      mx = fmaxf(mx, __shfl_xor(mx, 1, 64));
      mx = fmaxf(mx, __shfl_xor(mx, 2, 64));
      mx = fmaxf(mx, __shfl_xor(mx, 4, 64));
      mx = fmaxf(mx, __shfl_xor(mx, 8, 64));
      nm[i] = fmaxf(m_run[i], mx);
      alpha[i] = __expf(m_run[i] - nm[i]);
      m_run[i] = nm[i];
    }
    float rs[4] = {0.f, 0.f, 0.f, 0.f};
#pragma unroll
    for (int nt = 0; nt < 4; ++nt)
#pragma unroll
      for (int i = 0; i < 4; ++i) {
        float pv = __expf(sc[nt][i] - nm[i]);
        s_p[(w * 16 + lane_hi * 4 + i) * 72 + nt * 16 + lane_lo] = f2bf(pv);
        rs[i] += pv;
      }
#pragma unroll
    for (int i = 0; i < 4; ++i) {
      float s = rs[i];
      s += __shfl_xor(s, 1, 64);
      s += __shfl_xor(s, 2, 64);
      s += __shfl_xor(s, 4, 64);
      s += __shfl_xor(s, 8, 64);
      l_run[i] = l_run[i] * alpha[i] + s;
    }
#pragma unroll
    for (int j = 0; j < 6; ++j)
#pragma unroll
      for (int i = 0; i < 4; ++i) acc[j][i] *= alpha[i];
    const short8 pa0 = *(const short8*)&s_p[(w * 16 + lane_lo) * 72 + k0];
    const short8 pa1 = *(const short8*)&s_p[(w * 16 + lane_lo) * 72 + 32 + k0];
#pragma unroll
    for (int nt2 = 0; nt2 < 6; ++nt2) {
      const short8 xb0 = *(const short8*)&s_xt[((0 * 6 + nt2) * 64 + l) * 8];
      const short8 xb1 = *(const short8*)&s_xt[((1 * 6 + nt2) * 64 + l) * 8];
      acc[nt2] = MFMA16(pa0, xb0, acc[nt2]);
      acc[nt2] = MFMA16(pa1, xb1, acc[nt2]);
    }
  }
  float invl[4];
#pragma unroll
  for (int i = 0; i < 4; ++i) invl[i] = 1.f / l_run[i];
#pragma unroll
  for (int nt2 = 0; nt2 < 6; ++nt2)
#pragma unroll
    for (int i = 0; i < 4; ++i) {
      size_t o = ((size_t)bt * NN + rbase + w * 16 + lane_hi * 4 + i) * CC +
                 nt2 * 16 + lane_lo;
      Ax[o] = f2bf(acc[nt2][i] * invl[i]);
    }
}

// ------------- per-node weight matmul: g = xg @ (node_emb@Wp) + bias ---------
template <int MODE>
__global__ __launch_bounds__(256, 2) void k_nodemm(
    const float* __restrict__ x, const float* __restrict__ states,
    const float* __restrict__ zbuf, const unsigned short* __restrict__ Ax,
    const float* __restrict__ node_emb, const float* __restrict__ time_emb,
    const float* __restrict__ Wp, const float* __restrict__ bp,
    float* __restrict__ g) {
  __shared__ alignas(16) float s_W[192 * 64];   // [ki][o]
  __shared__ float s_xg[BT * 193];
  __shared__ float s_ne[DEE];
  __shared__ float s_te[BT * DEE];

  const int t = threadIdx.x;
  const int n = blockIdx.x;

  if (t < DEE) s_ne[t] = node_emb[n * DEE + t];
  for (int e = t; e < BT * DEE; e += 256) s_te[e] = time_emb[e];
  __syncthreads();

  float ne[DEE];
#pragma unroll
  for (int d = 0; d < DEE; ++d) ne[d] = s_ne[d];

  for (int k2 = 0; k2 < 48; ++k2) {
    int j = t + 256 * k2;
    float a = 0.f;
#pragma unroll
    for (int d = 0; d < DEE; ++d) a += ne[d] * Wp[(size_t)d * 12288 + j];
    s_W[j] = a;
  }

  for (int e = t; e < BT * 192; e += 256) {
    int btv = e / 192, c = e - btv * 192;
    float v;
    if (c < DII) {
      v = x[((size_t)btv * NN + n) * DII + c];
    } else if (c < CC) {
      v = states[(((size_t)(btv >> 1) * THH + (THH - KTT) + (btv & 1)) * NN + n) * DHD + (c - DII)];
      if (MODE == 1) v *= zbuf[((size_t)btv * NN + n) * DHD + (c - DII)];
    } else {
      v = bf2f(Ax[((size_t)btv * NN + n) * CC + (c - CC)]);
    }
    s_xg[btv * 193 + c] = v;
  }
  __syncthreads();

  const int btv = t >> 4;
  const int o0  = (t & 15) * 4;
  float y[4];
#pragma unroll
  for (int q = 0; q < 4; ++q) y[q] = 0.f;
#pragma unroll
  for (int d = 0; d < DEE; ++d) {
    float te = s_te[btv * DEE + d];
#pragma unroll
    for (int q = 0; q < 4; ++q) y[q] += te * bp[d * DHD + o0 + q];
  }
  const float* xr = &s_xg[btv * 193];
  for (int i = 0; i < 192; ++i) {
    float xv = xr[i];
    const float4 w4 = *(const float4*)&s_W[i * 64 + o0];
    y[0] += xv * w4.x; y[1] += xv * w4.y; y[2] += xv * w4.z; y[3] += xv * w4.w;
  }
  float* dst = &g[((size_t)btv * NN + n) * DHD + o0];
#pragma unroll
  for (int q = 0; q < 4; ++q) dst[q] = y[q];
}

// --------------------- LN + tiny MHA + activation / gate ---------------------
__device__ __forceinline__ float wsum64(float v) {
#pragma unroll
  for (int off = 32; off > 0; off >>= 1) v += __shfl_xor(v, off, 64);
  return v;
}
__device__ __forceinline__ float hsum16(float v) {
  v += __shfl_xor(v, 8, 64);
  v += __shfl_xor(v, 4, 64);
  v += __shfl_xor(v, 2, 64);
  v += __shfl_xor(v, 1, 64);
  return v;
}

template <int MODE>
__global__ void k_attn(const float* __restrict__ g,
                       const float* __restrict__ states,
                       const float* __restrict__ lnOg,
                       const float* __restrict__ lnOb,
                       const float* __restrict__ rbuf,
                       float* __restrict__ dst) {
  const int lane = threadIdx.x & 63;
  const int unit = blockIdx.x * 4 + (threadIdx.x >> 6);  // b*NN + n
  const int b = unit >> 11;
  const int n = unit & (NN - 1);

  float kv[THH];
#pragma unroll
  for (int s = 0; s < THH; ++s)
    kv[s] = states[(((size_t)b * THH + s) * NN + n) * DHD + lane];
  const float go = lnOg[lane], bo = lnOb[lane];

#pragma unroll
  for (int tt = 0; tt < KTT; ++tt) {
    const size_t oi = (((size_t)b * KTT + tt) * NN + n) * DHD + lane;
    const float gval = g[oi];
    float mean = wsum64(gval) * (1.f / 64.f);
    float dv = gval - mean;
    float var = wsum64(dv * dv) * (1.f / 64.f);
    float q = dv * (1.f / sqrtf(var + 1e-5f)) * go + bo;
    float sc[THH];
#pragma unroll
    for (int s = 0; s < THH; ++s) sc[s] = hsum16(q * kv[s]) * 0.25f;
    float mx = sc[0];
#pragma unroll
    for (int s = 1; s < THH; ++s) mx = fmaxf(mx, sc[s]);
    float sum = 0.f;
#pragma unroll
    for (int s = 0; s < THH; ++s) { sc[s] = __expf(sc[s] - mx); sum += sc[s]; }
    float o = 0.f;
#pragma unroll
    for (int s = 0; s < THH; ++s) o += sc[s] * kv[s];
    o /= sum;
    const float val = gval + o;
    if (MODE == 0) {
      dst[oi] = 1.f / (1.f + __expf(-val));
    } else {
      const float hc = tanhf(val);
      const float stl =
          states[(((size_t)b * THH + (THH - KTT) + tt) * NN + n) * DHD + lane];
      const float rr = rbuf[oi];
      dst[oi] = rr * stl + (1.f - rr) * hc;
    }
  }
}

extern "C" void kernel_launch(void* const* d_in, const int* in_sizes, int n_in,
                              void* d_out, int out_size, void* d_ws, size_t ws_size,
                              hipStream_t stream) {
  const float* x        = (const float*)d_in[0];
  const float* states   = (const float*)d_in[1];
  const float* node_emb = (const float*)d_in[2];
  const float* time_emb = (const float*)d_in[3];

  unsigned char* wsb = (unsigned char*)d_ws;
  unsigned*       ehZ = (unsigned*)(wsb);              // 2MB each
  unsigned*       elZ = (unsigned*)(wsb + (2u << 20));
  unsigned*       ehR = (unsigned*)(wsb + (4u << 20));
  unsigned*       elR = (unsigned*)(wsb + (6u << 20));
  unsigned short* AxZ = (unsigned short*)(wsb + (8u << 20));   // 6MB
  unsigned short* AxR = (unsigned short*)(wsb + (14u << 20));  // 6MB
  float*          gb  = (float*)(wsb + (20u << 20));           // 8MB
  float*          zb  = (float*)(wsb + (28u << 20));           // 8MB
  float*          rb  = (float*)(wsb + (36u << 20));           // 8MB
  float* outp = (float*)d_out;

  struct Gate { const float *W, *bias, *lAg, *lAb, *lOg, *lOb; };
  auto G = [&](int i) {
    return Gate{(const float*)d_in[i],     (const float*)d_in[i + 1],
                (const float*)d_in[i + 2], (const float*)d_in[i + 3],
                (const float*)d_in[i + 4], (const float*)d_in[i + 5]};
  };
  Gate gz = G(4), gr = G(10), gu = G(16);

  const int gridE = BT * NN / 256;
  const int gridA = BB * NN / 4;
  const int gridF = (NN / RT) * BT;   // 512, swizzled inside

  // ---- z and r gates (shared xin) ----
  k_emb2<<<gridE, 256, 0, stream>>>(node_emb, time_emb, gz.lAg, gz.lAb,
                                    gr.lAg, gr.lAb, ehZ, elZ, ehR, elR);
  k_flash_zr<<<gridF, 256, 0, stream>>>(ehZ, elZ, ehR, elR, x, states, AxZ, AxR);
  k_nodemm<0><<<NN, 256, 0, stream>>>(x, states, nullptr, AxZ, node_emb,
                                      time_emb, gz.W, gz.bias, gb);
  k_attn<0><<<gridA, 256, 0, stream>>>(gb, states, gz.lOg, gz.lOb, nullptr, zb);
  k_nodemm<0><<<NN, 256, 0, stream>>>(x, states, nullptr, AxR, node_emb,
                                      time_emb, gr.W, gr.bias, gb);
  k_attn<0><<<gridA, 256, 0, stream>>>(gb, states, gr.lOg, gr.lOb, nullptr, rb);
  // ---- u gate + final combine ----
  k_emb<<<gridE, 256, 0, stream>>>(node_emb, time_emb, gu.lAg, gu.lAb, ehZ, elZ);
  k_flash_u<<<gridF, 256, 0, stream>>>(ehZ, elZ, x, states, zb, AxZ);
  k_nodemm<1><<<NN, 256, 0, stream>>>(x, states, zb, AxZ, node_emb, time_emb,
                                      gu.W, gu.bias, gb);
  k_attn<1><<<gridA, 256, 0, stream>>>(gb, states, gu.lOg, gu.lOb, rb, outp);
}